// Round 2
// baseline (220.840 us; speedup 1.0000x reference)
//
#include <hip/hip_runtime.h>

#define NE 4000
#define NI 1000
#define NT 5000            // total neurons
#define PI_F 3.14159265358979323846f

#define NB_SIM ((NT + 63) / 64)     // 79 sim blocks (1 wave each, 1 neuron/lane)
#define NB_TOT 1024                 // rest are zero-filler blocks

// native vector type for __builtin_nontemporal_store (HIP float4 is rejected)
typedef float nf4 __attribute__((ext_vector_type(4)));
#define NTSTORE4(val, ptr) __builtin_nontemporal_store(*(const nf4*)&(val), (nf4*)(ptr))

// d_out layout (floats): [0,T) Out | [T, T+NT*T) V | next NT*T g | next NT*T spk

// One Euler step in u = tan(theta/2):  u += kk*I - hh + hh*u^2 ;  V = 3.5u - 58.5
#define U1(W, VV) { float a_ = fmaf(kk, (W), mh); float s_ = u + a_;    \
                    u = fmaf(hh * u, u, s_); umax = fmaxf(umax, u);     \
                    VV = fmaf(3.5f, u, -58.5f); }

// load one 16-step chunk (4 x dwordx4) into a named buffer set
#define LDm(P0, P1, P2, P3, cc) { const float* sp_ = ip + (cc) * 16;    \
    P0 = *(const float4*)(sp_);      P1 = *(const float4*)(sp_ + 4);    \
    P2 = *(const float4*)(sp_ + 8);  P3 = *(const float4*)(sp_ + 12); }

// process one 16-step chunk from a named buffer set; store V (4 x dwordx4, NT)
#define PROCm(P0, P1, P2, P3, cc) {                                     \
    float4 v0_, v1_, v2_, v3_; int t0_ = (cc) * 16;                     \
    if (t0_ == 0) { v0_.x = -58.5f; }   /* t=0: V=theta2V(0) */         \
    else          { U1(P0.x, v0_.x) }                                   \
    U1(P0.y, v0_.y) U1(P0.z, v0_.z) U1(P0.w, v0_.w)                     \
    U1(P1.x, v1_.x) U1(P1.y, v1_.y) U1(P1.z, v1_.z) U1(P1.w, v1_.w)     \
    U1(P2.x, v2_.x) U1(P2.y, v2_.y) U1(P2.z, v2_.z) U1(P2.w, v2_.w)     \
    U1(P3.x, v3_.x) U1(P3.y, v3_.y) U1(P3.z, v3_.z) U1(P3.w, v3_.w)     \
    float* dp_ = vrow + t0_;                                            \
    NTSTORE4(v0_, dp_);      NTSTORE4(v1_, dp_ + 4);                    \
    NTSTORE4(v2_, dp_ + 8);  NTSTORE4(v3_, dp_ + 12); }

__global__ __launch_bounds__(64) void sim_nospike(
    const float* __restrict__ Input, const float* __restrict__ dtp,
    float* __restrict__ out, int T, int* __restrict__ flags)
{
    const int lane = threadIdx.x;
    const int b = blockIdx.x;

    if (b >= NB_SIM) {                       // ---- zeroing path (full-chip BW) ----
        const nf4 z4 = {0.f, 0.f, 0.f, 0.f};
        long zidx = (long)(b - NB_SIM) * 64 + lane;
        long zstr = (long)(NB_TOT - NB_SIM) * 64;
        nf4* gz = (nf4*)(out + T + (long)NT * T);   // g+spk contiguous
        const long n4 = (long)NT * T / 2;
        for (long k = zidx; k < n4; k += zstr) __builtin_nontemporal_store(z4, gz + k);
        if (b == NB_SIM) {
            nf4* oz = (nf4*)out;
            for (int x = lane; x < T / 4; x += 64) __builtin_nontemporal_store(z4, oz + x);
        }
        return;
    }

    int i = b * 64 + lane; if (i >= NT) i = NT - 1;   // clamp: dup work, benign
    const float dt = dtp[0];
    const float gl = (i < NE) ? 0.08f : 0.1f;
    const float kk = (2.0f / 7.0f) * dt;     // C0*dt
    const float hh = 0.5f * gl * dt;
    const float mh = -hh;
    const float* ip = Input + (long)i * T;
    float* vrow = out + T + (long)i * T;
    float u = 0.f, umax = -1e30f;

    const int nch = ((T & 3) == 0) ? (T >> 4) : 0;    // 16-step chunks (62 @ T=1000)

    // 6 named buffer sets; loads issued 5 chunks (~960 compute cyc) before use,
    // covering the ~900-cycle HBM miss latency at 1 wave/CU (no TLP).
    float4 A0, A1, A2, A3, B0, B1, B2, B3, C0f, C1f, C2f, C3f;
    float4 D0, D1, D2, D3, E0, E1, E2, E3, F0, F1, F2, F3;

    if (nch > 0) LDm(A0, A1, A2, A3, 0);
    if (nch > 1) LDm(B0, B1, B2, B3, 1);
    if (nch > 2) LDm(C0f, C1f, C2f, C3f, 2);
    if (nch > 3) LDm(D0, D1, D2, D3, 3);
    if (nch > 4) LDm(E0, E1, E2, E3, 4);

    int c = 0;
    for (; c + 6 <= nch; c += 6) {
        LDm(F0, F1, F2, F3, c + 5);                       // c+5 < nch in-loop
        PROCm(A0, A1, A2, A3, c);
        if (c + 6 < nch)  LDm(A0, A1, A2, A3, c + 6);
        PROCm(B0, B1, B2, B3, c + 1);
        if (c + 7 < nch)  LDm(B0, B1, B2, B3, c + 7);
        PROCm(C0f, C1f, C2f, C3f, c + 2);
        if (c + 8 < nch)  LDm(C0f, C1f, C2f, C3f, c + 8);
        PROCm(D0, D1, D2, D3, c + 3);
        if (c + 9 < nch)  LDm(D0, D1, D2, D3, c + 9);
        PROCm(E0, E1, E2, E3, c + 4);
        if (c + 10 < nch) LDm(E0, E1, E2, E3, c + 10);
        PROCm(F0, F1, F2, F3, c + 5);
    }
    if (c < nch)     PROCm(A0, A1, A2, A3, c);
    if (c + 1 < nch) PROCm(B0, B1, B2, B3, c + 1);
    if (c + 2 < nch) PROCm(C0f, C1f, C2f, C3f, c + 2);
    if (c + 3 < nch) PROCm(D0, D1, D2, D3, c + 3);
    if (c + 4 < nch) PROCm(E0, E1, E2, E3, c + 4);

    // scalar tail (T=1000 -> 8 steps; also the generic path when T%4 != 0)
    for (int t = nch * 16; t < T; ++t) {
        float w = ip[t], v;
        if (t == 0) { v = -58.5f; }
        else        { U1(w, v) }
        vrow[t] = v;
    }

    // conservative spike flag: theta >= pi requires crossing u = tan(theta/2) >= 1
    unsigned long long ball = __ballot(umax >= 1.0f);
    if (lane == 0) flags[b] = (ball != 0ULL) ? 1 : 0;
}

// Exact sequential fallback (only executes if a spike was flagged).
__global__ __launch_bounds__(1024) void fallback(
    const float* __restrict__ Input, const float* __restrict__ conn,
    const float* __restrict__ Wout, const float* __restrict__ dtp,
    const int* __restrict__ tauEp, const int* __restrict__ tauIp,
    float* __restrict__ out, int T, const int* __restrict__ flags, int nb)
{
    __shared__ int any;
    const int tid = threadIdx.x;
    if (tid == 0) any = 0;
    __syncthreads();
    if (tid < nb && flags[tid] != 0) any = 1;
    __syncthreads();
    if (any == 0) return;                   // uniform: optimistic path valid

    const float dt = *dtp;
    const float tauE = (float)(*tauEp), tauI = (float)(*tauIp);
    const float C0 = (float)(2.0 / 7.0);
    const float C1 = (float)(117.0 / 7.0);
    const float C2 = (float)(-23.0 / 7.0);
    const int BLK = 1024;
    const int K = 5;                        // 5*1024 >= 5000

    __shared__ int cntE, cntI;
    __shared__ int listE[NE];
    __shared__ int listI[NI];
    __shared__ float red[1024];

    float gA[K], gB[K], gC[K], ph[K];
    for (int k = 0; k < K; ++k) { gA[k] = gB[k] = gC[k] = 0.f; ph[k] = 0.f; }
    if (tid == 0) { cntE = 0; cntI = 0; }

    float* Vout = out + T;
    float* Gout = out + T + (long)NT * T;
    float* Sout = out + T + 2L * (long)NT * T;
    for (int k = 0; k < K; ++k) {
        int i = tid + k * BLK;
        if (i < NT) Vout[(long)i * T] = -58.5f;
    }
    __syncthreads();

    for (int t = 1; t < T; ++t) {
        int nEs = cntE, nIs = cntI;         // spikes from step t-1
        float outpart = 0.f;
        for (int k = 0; k < K; ++k) {
            int i = tid + k * BLK;
            if (i >= NT) break;
            const float* crow = conn + (long)i * NT;
            float mA = 0.f, mB = 0.f;
            for (int j = 0; j < nEs; ++j) mA += crow[listE[j]];
            for (int j = 0; j < nIs; ++j) mB += crow[listI[j]];
            bool isE = i < NE;
            float tau = isE ? tauE : tauI;
            float gpA = isE ? 0.004069f : 0.003276f;
            float gpB = isE ? 0.02672f  : 0.02138f;
            gA[k] = gA[k] + (-gA[k] / tau + gpA * mA) * dt;
            gB[k] = gB[k] + (-gB[k] / tau + gpB * mB) * dt;
            gC[k] = gC[k] + (-gC[k] / tau + gpA * mA + gpB * mB) * dt;
            Gout[(long)i * T + t] = gC[k];
            outpart += gC[k] * Wout[i];
        }
        __syncthreads();                    // all done reading lists
        if (tid == 0) { cntE = 0; cntI = 0; }
        red[tid] = outpart;
        __syncthreads();
        for (int sd = BLK / 2; sd > 0; sd >>= 1) {
            if (tid < sd) red[tid] += red[tid + sd];
            __syncthreads();
        }
        if (tid == 0) out[t] = red[0] / (float)NT;

        for (int k = 0; k < K; ++k) {
            int i = tid + k * BLK;
            if (i >= NT) break;
            bool isE = i < NE;
            float gl = isE ? 0.08f : 0.1f;
            float inp = Input[(long)i * T + t];
            float s, c;
            sincosf(ph[k], &s, &c);
            float ph2 = ph[k] + (-gl * c + C0 * (1.f + c) * inp
                                 + gA[k] * (C1 * (1.f + c) - s)
                                 + gB[k] * (C2 * (1.f + c) - s)) * dt;
            float spkv = 0.f;
            if (ph2 >= PI_F) {
                spkv = 1.f;
                ph2 -= 2.f * PI_F;
                int pos = isE ? atomicAdd(&cntE, 1) : atomicAdd(&cntI, 1);
                if (isE) listE[pos] = i; else listI[pos] = i;
            }
            ph[k] = ph2;
            Sout[(long)i * T + t] = spkv;
            Vout[(long)i * T + t] = fmaf(3.5f, tanf(ph2 * 0.5f), -58.5f);
        }
        __syncthreads();                    // lists complete for next step
    }
}

extern "C" void kernel_launch(void* const* d_in, const int* in_sizes, int n_in,
                              void* d_out, int out_size, void* d_ws, size_t ws_size,
                              hipStream_t stream)
{
    const float* dt    = (const float*)d_in[0];
    const float* Input = (const float*)d_in[1];
    const float* conn  = (const float*)d_in[2];
    const float* Wout  = (const float*)d_in[3];
    const int*   tauE  = (const int*)d_in[6];
    const int*   tauI  = (const int*)d_in[7];
    int T = in_sizes[1] / NT;
    float* out = (float*)d_out;
    int* flags = (int*)d_ws;

    sim_nospike<<<NB_TOT, 64, 0, stream>>>(Input, dt, out, T, flags);
    fallback<<<1, 1024, 0, stream>>>(Input, conn, Wout, dt, tauE, tauI, out, T, flags, NB_SIM);
}

// Round 3
// 207.360 us; speedup vs baseline: 1.0650x; 1.0650x over previous
//
#include <hip/hip_runtime.h>

#define NE 4000
#define NI 1000
#define NT 5000            // total neurons
#define PI_F 3.14159265358979323846f

#define NB_SIM ((NT + 63) / 64)     // 79 sim blocks (1 wave each, 1 neuron/lane)
#define NB_TOT 1024                 // rest are zero-filler blocks

// native vector type for __builtin_nontemporal_store (HIP float4 is rejected)
typedef float nf4 __attribute__((ext_vector_type(4)));

// d_out layout (floats): [0,T) Out | [T, T+NT*T) V | next NT*T g | next NT*T spk

// One Euler step in u = tan(theta/2):  u += kk*I - hh + hh*u^2 ;  V = 3.5u - 58.5
#define U1(W, VV) { float a_ = fmaf(kk, (W), mh); float s_ = u + a_;    \
                    u = fmaf(hh * u, u, s_); umax = fmaxf(umax, u);     \
                    VV = fmaf(3.5f, u, -58.5f); }

// load one 16-step chunk (4 x dwordx4) into a named buffer set
#define LDm(P0, P1, P2, P3, cc) { const float* sp_ = ip + (cc) * 16;    \
    P0 = *(const float4*)(sp_);      P1 = *(const float4*)(sp_ + 4);    \
    P2 = *(const float4*)(sp_ + 8);  P3 = *(const float4*)(sp_ + 12); }

// process one 16-step chunk from a named buffer set; store V.
// REGULAR stores here (not nontemporal): each lane's 4 dwordx4 cover one
// private 64B line, 64 lines/wave-instr — L2 write-back merges them into
// full lines. NT stores bypass L2 -> partial-line HBM writes -> store
// queue backpressure on vmcnt stalled the prefetch loads (R2: 69.9us,
// VALUBusy 1.4%). Reverted.
#define PROCm(P0, P1, P2, P3, cc) {                                     \
    float4 v0_, v1_, v2_, v3_; int t0_ = (cc) * 16;                     \
    if (t0_ == 0) { v0_.x = -58.5f; }   /* t=0: V=theta2V(0) */         \
    else          { U1(P0.x, v0_.x) }                                   \
    U1(P0.y, v0_.y) U1(P0.z, v0_.z) U1(P0.w, v0_.w)                     \
    U1(P1.x, v1_.x) U1(P1.y, v1_.y) U1(P1.z, v1_.z) U1(P1.w, v1_.w)     \
    U1(P2.x, v2_.x) U1(P2.y, v2_.y) U1(P2.z, v2_.z) U1(P2.w, v2_.w)     \
    U1(P3.x, v3_.x) U1(P3.y, v3_.y) U1(P3.z, v3_.z) U1(P3.w, v3_.w)     \
    float* dp_ = vrow + t0_;                                            \
    *(float4*)(dp_)     = v0_;  *(float4*)(dp_ + 4)  = v1_;             \
    *(float4*)(dp_ + 8) = v2_;  *(float4*)(dp_ + 12) = v3_; }

__global__ __launch_bounds__(64) void sim_nospike(
    const float* __restrict__ Input, const float* __restrict__ dtp,
    float* __restrict__ out, int T, int* __restrict__ flags)
{
    const int lane = threadIdx.x;
    const int b = blockIdx.x;

    if (b >= NB_SIM) {                       // ---- zeroing path (full-chip BW) ----
        // NT stores kept here: consecutive lanes write consecutive float4s
        // -> 1024B contiguous per wave instr = 16 full 64B lines, safe for
        // nontemporal, and avoids polluting L2 with 60MB of zeros.
        const nf4 z4 = {0.f, 0.f, 0.f, 0.f};
        long zidx = (long)(b - NB_SIM) * 64 + lane;
        long zstr = (long)(NB_TOT - NB_SIM) * 64;
        nf4* gz = (nf4*)(out + T + (long)NT * T);   // g+spk contiguous
        const long n4 = (long)NT * T / 2;
        for (long k = zidx; k < n4; k += zstr) __builtin_nontemporal_store(z4, gz + k);
        if (b == NB_SIM) {
            nf4* oz = (nf4*)out;
            for (int x = lane; x < T / 4; x += 64) __builtin_nontemporal_store(z4, oz + x);
        }
        return;
    }

    int i = b * 64 + lane; if (i >= NT) i = NT - 1;   // clamp: dup work, benign
    const float dt = dtp[0];
    const float gl = (i < NE) ? 0.08f : 0.1f;
    const float kk = (2.0f / 7.0f) * dt;     // C0*dt
    const float hh = 0.5f * gl * dt;
    const float mh = -hh;
    const float* ip = Input + (long)i * T;
    float* vrow = out + T + (long)i * T;
    float u = 0.f, umax = -1e30f;

    const int nch = ((T & 3) == 0) ? (T >> 4) : 0;    // 16-step chunks (62 @ T=1000)

    // 6 named buffer sets; loads issued 5 chunks ahead, covering the
    // ~900-cycle HBM miss latency at 1 wave/CU (no TLP).
    float4 A0, A1, A2, A3, B0, B1, B2, B3, C0f, C1f, C2f, C3f;
    float4 D0, D1, D2, D3, E0, E1, E2, E3, F0, F1, F2, F3;

    if (nch > 0) LDm(A0, A1, A2, A3, 0);
    if (nch > 1) LDm(B0, B1, B2, B3, 1);
    if (nch > 2) LDm(C0f, C1f, C2f, C3f, 2);
    if (nch > 3) LDm(D0, D1, D2, D3, 3);
    if (nch > 4) LDm(E0, E1, E2, E3, 4);

    int c = 0;
    for (; c + 6 <= nch; c += 6) {
        LDm(F0, F1, F2, F3, c + 5);                       // c+5 < nch in-loop
        PROCm(A0, A1, A2, A3, c);
        if (c + 6 < nch)  LDm(A0, A1, A2, A3, c + 6);
        PROCm(B0, B1, B2, B3, c + 1);
        if (c + 7 < nch)  LDm(B0, B1, B2, B3, c + 7);
        PROCm(C0f, C1f, C2f, C3f, c + 2);
        if (c + 8 < nch)  LDm(C0f, C1f, C2f, C3f, c + 8);
        PROCm(D0, D1, D2, D3, c + 3);
        if (c + 9 < nch)  LDm(D0, D1, D2, D3, c + 9);
        PROCm(E0, E1, E2, E3, c + 4);
        if (c + 10 < nch) LDm(E0, E1, E2, E3, c + 10);
        PROCm(F0, F1, F2, F3, c + 5);
    }
    if (c < nch)     PROCm(A0, A1, A2, A3, c);
    if (c + 1 < nch) PROCm(B0, B1, B2, B3, c + 1);
    if (c + 2 < nch) PROCm(C0f, C1f, C2f, C3f, c + 2);
    if (c + 3 < nch) PROCm(D0, D1, D2, D3, c + 3);
    if (c + 4 < nch) PROCm(E0, E1, E2, E3, c + 4);

    // scalar tail (T=1000 -> 8 steps; also the generic path when T%4 != 0)
    for (int t = nch * 16; t < T; ++t) {
        float w = ip[t], v;
        if (t == 0) { v = -58.5f; }
        else        { U1(w, v) }
        vrow[t] = v;
    }

    // conservative spike flag: theta >= pi requires crossing u = tan(theta/2) >= 1
    unsigned long long ball = __ballot(umax >= 1.0f);
    if (lane == 0) flags[b] = (ball != 0ULL) ? 1 : 0;
}

// Exact sequential fallback (only executes if a spike was flagged).
__global__ __launch_bounds__(1024) void fallback(
    const float* __restrict__ Input, const float* __restrict__ conn,
    const float* __restrict__ Wout, const float* __restrict__ dtp,
    const int* __restrict__ tauEp, const int* __restrict__ tauIp,
    float* __restrict__ out, int T, const int* __restrict__ flags, int nb)
{
    __shared__ int any;
    const int tid = threadIdx.x;
    if (tid == 0) any = 0;
    __syncthreads();
    if (tid < nb && flags[tid] != 0) any = 1;
    __syncthreads();
    if (any == 0) return;                   // uniform: optimistic path valid

    const float dt = *dtp;
    const float tauE = (float)(*tauEp), tauI = (float)(*tauIp);
    const float C0 = (float)(2.0 / 7.0);
    const float C1 = (float)(117.0 / 7.0);
    const float C2 = (float)(-23.0 / 7.0);
    const int BLK = 1024;
    const int K = 5;                        // 5*1024 >= 5000

    __shared__ int cntE, cntI;
    __shared__ int listE[NE];
    __shared__ int listI[NI];
    __shared__ float red[1024];

    float gA[K], gB[K], gC[K], ph[K];
    for (int k = 0; k < K; ++k) { gA[k] = gB[k] = gC[k] = 0.f; ph[k] = 0.f; }
    if (tid == 0) { cntE = 0; cntI = 0; }

    float* Vout = out + T;
    float* Gout = out + T + (long)NT * T;
    float* Sout = out + T + 2L * (long)NT * T;
    for (int k = 0; k < K; ++k) {
        int i = tid + k * BLK;
        if (i < NT) Vout[(long)i * T] = -58.5f;
    }
    __syncthreads();

    for (int t = 1; t < T; ++t) {
        int nEs = cntE, nIs = cntI;         // spikes from step t-1
        float outpart = 0.f;
        for (int k = 0; k < K; ++k) {
            int i = tid + k * BLK;
            if (i >= NT) break;
            const float* crow = conn + (long)i * NT;
            float mA = 0.f, mB = 0.f;
            for (int j = 0; j < nEs; ++j) mA += crow[listE[j]];
            for (int j = 0; j < nIs; ++j) mB += crow[listI[j]];
            bool isE = i < NE;
            float tau = isE ? tauE : tauI;
            float gpA = isE ? 0.004069f : 0.003276f;
            float gpB = isE ? 0.02672f  : 0.02138f;
            gA[k] = gA[k] + (-gA[k] / tau + gpA * mA) * dt;
            gB[k] = gB[k] + (-gB[k] / tau + gpB * mB) * dt;
            gC[k] = gC[k] + (-gC[k] / tau + gpA * mA + gpB * mB) * dt;
            Gout[(long)i * T + t] = gC[k];
            outpart += gC[k] * Wout[i];
        }
        __syncthreads();                    // all done reading lists
        if (tid == 0) { cntE = 0; cntI = 0; }
        red[tid] = outpart;
        __syncthreads();
        for (int sd = BLK / 2; sd > 0; sd >>= 1) {
            if (tid < sd) red[tid] += red[tid + sd];
            __syncthreads();
        }
        if (tid == 0) out[t] = red[0] / (float)NT;

        for (int k = 0; k < K; ++k) {
            int i = tid + k * BLK;
            if (i >= NT) break;
            bool isE = i < NE;
            float gl = isE ? 0.08f : 0.1f;
            float inp = Input[(long)i * T + t];
            float s, c;
            sincosf(ph[k], &s, &c);
            float ph2 = ph[k] + (-gl * c + C0 * (1.f + c) * inp
                                 + gA[k] * (C1 * (1.f + c) - s)
                                 + gB[k] * (C2 * (1.f + c) - s)) * dt;
            float spkv = 0.f;
            if (ph2 >= PI_F) {
                spkv = 1.f;
                ph2 -= 2.f * PI_F;
                int pos = isE ? atomicAdd(&cntE, 1) : atomicAdd(&cntI, 1);
                if (isE) listE[pos] = i; else listI[pos] = i;
            }
            ph[k] = ph2;
            Sout[(long)i * T + t] = spkv;
            Vout[(long)i * T + t] = fmaf(3.5f, tanf(ph2 * 0.5f), -58.5f);
        }
        __syncthreads();                    // lists complete for next step
    }
}

extern "C" void kernel_launch(void* const* d_in, const int* in_sizes, int n_in,
                              void* d_out, int out_size, void* d_ws, size_t ws_size,
                              hipStream_t stream)
{
    const float* dt    = (const float*)d_in[0];
    const float* Input = (const float*)d_in[1];
    const float* conn  = (const float*)d_in[2];
    const float* Wout  = (const float*)d_in[3];
    const int*   tauE  = (const int*)d_in[6];
    const int*   tauI  = (const int*)d_in[7];
    int T = in_sizes[1] / NT;
    float* out = (float*)d_out;
    int* flags = (int*)d_ws;

    sim_nospike<<<NB_TOT, 64, 0, stream>>>(Input, dt, out, T, flags);
    fallback<<<1, 1024, 0, stream>>>(Input, conn, Wout, dt, tauE, tauI, out, T, flags, NB_SIM);
}

// Round 4
// 197.749 us; speedup vs baseline: 1.1168x; 1.0486x over previous
//
#include <hip/hip_runtime.h>

#define NE 4000
#define NI 1000
#define NT 5000            // total neurons
#define PI_F 3.14159265358979323846f

#define NB_SIM ((NT + 63) / 64)     // 79 sim blocks (1 wave each, 1 neuron/lane)
#define NB_TOT 1024                 // rest are zero-filler blocks

// native vector type for __builtin_nontemporal_store (HIP float4 is rejected)
typedef float nf4 __attribute__((ext_vector_type(4)));

#define LROW 132   // LDS row: 128 floats (8 chunks of V) + 4 pad (bank spread)

// d_out layout (floats): [0,T) Out | [T, T+NT*T) V | next NT*T g | next NT*T spk

// One Euler step in u = tan(theta/2):  u += kk*I - hh + hh*u^2 ;  V = 3.5u - 58.5
#define U1(W, VV) { float a_ = fmaf(kk, (W), mh); float s_ = u + a_;    \
                    u = fmaf(hh * u, u, s_); umax = fmaxf(umax, u);     \
                    VV = fmaf(3.5f, u, -58.5f); }

// load one 16-step chunk (4 x dwordx4 = exactly one 64B line per lane)
#define LDm(P0, P1, P2, P3, cc) { const float* sp_ = ip + (cc) * 16;    \
    P0 = *(const float4*)(sp_);      P1 = *(const float4*)(sp_ + 4);    \
    P2 = *(const float4*)(sp_ + 8);  P3 = *(const float4*)(sp_ + 12); }

// compute 16 steps; write V into LDS (row = lane, slot = chunk & 7).
// ds_write lives on lgkmcnt -> store traffic no longer clogs the vmcnt
// queue that the prefetch loads wait on (R2 evidence: scattered global
// stores -> 1.56 TB/s, VALUBusy 1.4%, ~95% stall).
#define PROCm(P0, P1, P2, P3, cc) {                                     \
    float4 v0_, v1_, v2_, v3_; int t0_ = (cc) * 16;                     \
    if (t0_ == 0) { v0_.x = -58.5f; }   /* t=0: V=theta2V(0) */         \
    else          { U1(P0.x, v0_.x) }                                   \
    U1(P0.y, v0_.y) U1(P0.z, v0_.z) U1(P0.w, v0_.w)                     \
    U1(P1.x, v1_.x) U1(P1.y, v1_.y) U1(P1.z, v1_.z) U1(P1.w, v1_.w)     \
    U1(P2.x, v2_.x) U1(P2.y, v2_.y) U1(P2.z, v2_.z) U1(P2.w, v2_.w)     \
    U1(P3.x, v3_.x) U1(P3.y, v3_.y) U1(P3.z, v3_.z) U1(P3.w, v3_.w)     \
    float* lp_ = &vbuf[lane][((cc) & 7) * 16];                          \
    *(float4*)(lp_)     = v0_;  *(float4*)(lp_ + 4)  = v1_;             \
    *(float4*)(lp_ + 8) = v2_;  *(float4*)(lp_ + 12) = v3_; }

// dump chunks [cs, ce) from LDS to global, coalesced: one store instr
// covers 2 rows x 32 lanes x 16B of contiguous full 64B lines (16 line
// transactions vs 64 partial-line for the old per-lane scatter).
#define DUMP(cs, ce) {                                                  \
    const int nf4_ = ((ce) - (cs)) * 4;                                 \
    const int l5_ = lane & 31, sub_ = lane >> 5;                        \
    if (l5_ < nf4_) {                                                   \
        for (int r_ = 0; r_ + sub_ < nrow; r_ += 2) {                   \
            int rr_ = r_ + sub_;                                        \
            float4 val_ = *(const float4*)&vbuf[rr_][l5_ * 4];          \
            *(float4*)(out + T + (long)(base + rr_) * T                 \
                       + (cs) * 16 + l5_ * 4) = val_;                   \
        }                                                               \
    }                                                                   \
}

// guarded pipeline step for the epilogue
#define GSTEP(k, PP0, PP1, PP2, PP3, LL0, LL1, LL2, LL3)                \
  if (c + (k) < nch) {                                                  \
    if (c + (k) + 5 < nch) LDm(LL0, LL1, LL2, LL3, c + (k) + 5)         \
    PROCm(PP0, PP1, PP2, PP3, c + (k))                                  \
    if (((c + (k) + 1) & 7) == 0) DUMP(c + (k) + 1 - 8, c + (k) + 1)    \
  }

__global__ __launch_bounds__(64) void sim_nospike(
    const float* __restrict__ Input, const float* __restrict__ dtp,
    float* __restrict__ out, int T, int* __restrict__ flags)
{
    const int lane = threadIdx.x;
    const int b = blockIdx.x;
    __shared__ float vbuf[64][LROW];       // 33.8 KB; unused by zero path

    if (b >= NB_SIM) {                       // ---- zeroing path (full-chip BW) ----
        // NT stores: consecutive lanes write consecutive float4s -> 1024B
        // contiguous per wave instr = 16 full 64B lines; also avoids
        // polluting L2 with 60MB of zeros.
        const nf4 z4 = {0.f, 0.f, 0.f, 0.f};
        long zidx = (long)(b - NB_SIM) * 64 + lane;
        long zstr = (long)(NB_TOT - NB_SIM) * 64;
        nf4* gz = (nf4*)(out + T + (long)NT * T);   // g+spk contiguous
        const long n4 = (long)NT * T / 2;
        for (long k = zidx; k < n4; k += zstr) __builtin_nontemporal_store(z4, gz + k);
        if (b == NB_SIM) {
            nf4* oz = (nf4*)out;
            for (int x = lane; x < T / 4; x += 64) __builtin_nontemporal_store(z4, oz + x);
        }
        return;
    }

    const int base = b * 64;
    const int nrow = (NT - base < 64) ? (NT - base) : 64;
    int i = base + lane; if (i >= NT) i = NT - 1;   // clamp: dup work, benign
    const float dt = dtp[0];
    const float gl = (i < NE) ? 0.08f : 0.1f;
    const float kk = (2.0f / 7.0f) * dt;     // C0*dt
    const float hh = 0.5f * gl * dt;
    const float mh = -hh;
    const float* ip = Input + (long)i * T;
    float* vrow = out + T + (long)i * T;     // scalar-tail path only
    float u = 0.f, umax = -1e30f;

    const int nch = ((T & 3) == 0) ? (T >> 4) : 0;    // 16-step chunks (62 @ T=1000)

    // 8 buffer slots, 5 chunks in flight ahead of use (~1100 cyc cover at
    // ~224 cyc/chunk incl. ds_write) -- covers ~900-cyc HBM miss latency.
    float4 s00,s01,s02,s03, s10,s11,s12,s13, s20,s21,s22,s23, s30,s31,s32,s33,
           s40,s41,s42,s43, s50,s51,s52,s53, s60,s61,s62,s63, s70,s71,s72,s73;

    if (nch > 0) LDm(s00,s01,s02,s03, 0)
    if (nch > 1) LDm(s10,s11,s12,s13, 1)
    if (nch > 2) LDm(s20,s21,s22,s23, 2)
    if (nch > 3) LDm(s30,s31,s32,s33, 3)
    if (nch > 4) LDm(s40,s41,s42,s43, 4)

    int c = 0;
    // stationary period-8 rotation: PROC slot k eats chunk c+k, LD slot
    // (k+5)%8 fetches chunk c+k+5. After 8 steps slots 0-4 again hold the
    // next 5 prefetched chunks. Dump the finished 8-chunk segment at the
    // end of each iteration (32 dump stores -> younger-op count < 63, so
    // counted vmcnt waits never force a pipeline drain).
    for (; c + 13 <= nch; c += 8) {
        LDm(s50,s51,s52,s53, c+5)   PROCm(s00,s01,s02,s03, c)
        LDm(s60,s61,s62,s63, c+6)   PROCm(s10,s11,s12,s13, c+1)
        LDm(s70,s71,s72,s73, c+7)   PROCm(s20,s21,s22,s23, c+2)
        LDm(s00,s01,s02,s03, c+8)   PROCm(s30,s31,s32,s33, c+3)
        LDm(s10,s11,s12,s13, c+9)   PROCm(s40,s41,s42,s43, c+4)
        LDm(s20,s21,s22,s23, c+10)  PROCm(s50,s51,s52,s53, c+5)
        LDm(s30,s31,s32,s33, c+11)  PROCm(s60,s61,s62,s63, c+6)
        LDm(s40,s41,s42,s43, c+12)  PROCm(s70,s71,s72,s73, c+7)
        DUMP(c, c + 8)
    }
    // guarded epilogue: up to 12 remaining chunks
    GSTEP(0,  s00,s01,s02,s03, s50,s51,s52,s53)
    GSTEP(1,  s10,s11,s12,s13, s60,s61,s62,s63)
    GSTEP(2,  s20,s21,s22,s23, s70,s71,s72,s73)
    GSTEP(3,  s30,s31,s32,s33, s00,s01,s02,s03)
    GSTEP(4,  s40,s41,s42,s43, s10,s11,s12,s13)
    GSTEP(5,  s50,s51,s52,s53, s20,s21,s22,s23)
    GSTEP(6,  s60,s61,s62,s63, s30,s31,s32,s33)
    GSTEP(7,  s70,s71,s72,s73, s40,s41,s42,s43)
    GSTEP(8,  s00,s01,s02,s03, s50,s51,s52,s53)
    GSTEP(9,  s10,s11,s12,s13, s60,s61,s62,s63)
    GSTEP(10, s20,s21,s22,s23, s70,s71,s72,s73)
    GSTEP(11, s30,s31,s32,s33, s00,s01,s02,s03)

    { const int cd = nch & ~7; if (nch > cd) DUMP(cd, nch) }

    // scalar tail (T=1000 -> 8 steps; also the generic path when T%4 != 0)
    for (int t = nch * 16; t < T; ++t) {
        float w = ip[t], v;
        if (t == 0) { v = -58.5f; }
        else        { U1(w, v) }
        vrow[t] = v;
    }

    // conservative spike flag: theta >= pi requires crossing u = tan(theta/2) >= 1
    unsigned long long ball = __ballot(umax >= 1.0f);
    if (lane == 0) flags[b] = (ball != 0ULL) ? 1 : 0;
}

// Exact sequential fallback (only executes if a spike was flagged).
__global__ __launch_bounds__(1024) void fallback(
    const float* __restrict__ Input, const float* __restrict__ conn,
    const float* __restrict__ Wout, const float* __restrict__ dtp,
    const int* __restrict__ tauEp, const int* __restrict__ tauIp,
    float* __restrict__ out, int T, const int* __restrict__ flags, int nb)
{
    __shared__ int any;
    const int tid = threadIdx.x;
    if (tid == 0) any = 0;
    __syncthreads();
    if (tid < nb && flags[tid] != 0) any = 1;
    __syncthreads();
    if (any == 0) return;                   // uniform: optimistic path valid

    const float dt = *dtp;
    const float tauE = (float)(*tauEp), tauI = (float)(*tauIp);
    const float C0 = (float)(2.0 / 7.0);
    const float C1 = (float)(117.0 / 7.0);
    const float C2 = (float)(-23.0 / 7.0);
    const int BLK = 1024;
    const int K = 5;                        // 5*1024 >= 5000

    __shared__ int cntE, cntI;
    __shared__ int listE[NE];
    __shared__ int listI[NI];
    __shared__ float red[1024];

    float gA[K], gB[K], gC[K], ph[K];
    for (int k = 0; k < K; ++k) { gA[k] = gB[k] = gC[k] = 0.f; ph[k] = 0.f; }
    if (tid == 0) { cntE = 0; cntI = 0; }

    float* Vout = out + T;
    float* Gout = out + T + (long)NT * T;
    float* Sout = out + T + 2L * (long)NT * T;
    for (int k = 0; k < K; ++k) {
        int i = tid + k * BLK;
        if (i < NT) Vout[(long)i * T] = -58.5f;
    }
    __syncthreads();

    for (int t = 1; t < T; ++t) {
        int nEs = cntE, nIs = cntI;         // spikes from step t-1
        float outpart = 0.f;
        for (int k = 0; k < K; ++k) {
            int i = tid + k * BLK;
            if (i >= NT) break;
            const float* crow = conn + (long)i * NT;
            float mA = 0.f, mB = 0.f;
            for (int j = 0; j < nEs; ++j) mA += crow[listE[j]];
            for (int j = 0; j < nIs; ++j) mB += crow[listI[j]];
            bool isE = i < NE;
            float tau = isE ? tauE : tauI;
            float gpA = isE ? 0.004069f : 0.003276f;
            float gpB = isE ? 0.02672f  : 0.02138f;
            gA[k] = gA[k] + (-gA[k] / tau + gpA * mA) * dt;
            gB[k] = gB[k] + (-gB[k] / tau + gpB * mB) * dt;
            gC[k] = gC[k] + (-gC[k] / tau + gpA * mA + gpB * mB) * dt;
            Gout[(long)i * T + t] = gC[k];
            outpart += gC[k] * Wout[i];
        }
        __syncthreads();                    // all done reading lists
        if (tid == 0) { cntE = 0; cntI = 0; }
        red[tid] = outpart;
        __syncthreads();
        for (int sd = BLK / 2; sd > 0; sd >>= 1) {
            if (tid < sd) red[tid] += red[tid + sd];
            __syncthreads();
        }
        if (tid == 0) out[t] = red[0] / (float)NT;

        for (int k = 0; k < K; ++k) {
            int i = tid + k * BLK;
            if (i >= NT) break;
            bool isE = i < NE;
            float gl = isE ? 0.08f : 0.1f;
            float inp = Input[(long)i * T + t];
            float s, c;
            sincosf(ph[k], &s, &c);
            float ph2 = ph[k] + (-gl * c + C0 * (1.f + c) * inp
                                 + gA[k] * (C1 * (1.f + c) - s)
                                 + gB[k] * (C2 * (1.f + c) - s)) * dt;
            float spkv = 0.f;
            if (ph2 >= PI_F) {
                spkv = 1.f;
                ph2 -= 2.f * PI_F;
                int pos = isE ? atomicAdd(&cntE, 1) : atomicAdd(&cntI, 1);
                if (isE) listE[pos] = i; else listI[pos] = i;
            }
            ph[k] = ph2;
            Sout[(long)i * T + t] = spkv;
            Vout[(long)i * T + t] = fmaf(3.5f, tanf(ph2 * 0.5f), -58.5f);
        }
        __syncthreads();                    // lists complete for next step
    }
}

extern "C" void kernel_launch(void* const* d_in, const int* in_sizes, int n_in,
                              void* d_out, int out_size, void* d_ws, size_t ws_size,
                              hipStream_t stream)
{
    const float* dt    = (const float*)d_in[0];
    const float* Input = (const float*)d_in[1];
    const float* conn  = (const float*)d_in[2];
    const float* Wout  = (const float*)d_in[3];
    const int*   tauE  = (const int*)d_in[6];
    const int*   tauI  = (const int*)d_in[7];
    int T = in_sizes[1] / NT;
    float* out = (float*)d_out;
    int* flags = (int*)d_ws;

    sim_nospike<<<NB_TOT, 64, 0, stream>>>(Input, dt, out, T, flags);
    fallback<<<1, 1024, 0, stream>>>(Input, conn, Wout, dt, tauE, tauI, out, T, flags, NB_SIM);
}

// Round 5
// 194.373 us; speedup vs baseline: 1.1362x; 1.0174x over previous
//
#include <hip/hip_runtime.h>

#define NE 4000
#define NI 1000
#define NT 5000            // total neurons
#define PI_F 3.14159265358979323846f

// 32 neurons per sim block: doubles the CU count carrying the memory
// stream (157 CUs vs 79). Wave64 issue cost is independent of active
// lanes, so per-wave compute time is unchanged; per-CU memory demand
// halves. Lanes 32-63 duplicate lanes 0-31 (coalesced dup loads,
// same-address/same-data LDS writes -> benign).
#define NPB 32
#define NB_SIM ((NT + NPB - 1) / NPB)   // 157 sim blocks
#define NB_TOT 1024                     // rest are zero-filler blocks

// native vector type for __builtin_nontemporal_store (HIP float4 is rejected)
typedef float nf4 __attribute__((ext_vector_type(4)));

#define LROW 132   // LDS row: 128 floats (8 chunks of V) + 4 pad (bank spread)

// d_out layout (floats): [0,T) Out | [T, T+NT*T) V | next NT*T g | next NT*T spk

// One Euler step in u = tan(theta/2):  u += kk*I - hh + hh*u^2 ;  V = 3.5u - 58.5
#define U1(W, VV) { float a_ = fmaf(kk, (W), mh); float s_ = u + a_;    \
                    u = fmaf(hh * u, u, s_); umax = fmaxf(umax, u);     \
                    VV = fmaf(3.5f, u, -58.5f); }

// load one 16-step chunk (4 x dwordx4 = exactly one 64B line per lane;
// half-waves duplicate rows -> still 32 unique lines per instr)
#define LDm(P0, P1, P2, P3, cc) { const float* sp_ = ip + (cc) * 16;    \
    P0 = *(const float4*)(sp_);      P1 = *(const float4*)(sp_ + 4);    \
    P2 = *(const float4*)(sp_ + 8);  P3 = *(const float4*)(sp_ + 12); }

// compute 16 steps; write V into LDS (row = lane&31, slot = chunk & 7).
// ds_write lives on lgkmcnt -> store traffic doesn't clog the vmcnt
// queue the prefetch loads wait on (R2 evidence: scattered global
// stores -> 1.56 TB/s, VALUBusy 1.4%, ~95% stall).
#define PROCm(P0, P1, P2, P3, cc) {                                     \
    float4 v0_, v1_, v2_, v3_; int t0_ = (cc) * 16;                     \
    if (t0_ == 0) { v0_.x = -58.5f; }   /* t=0: V=theta2V(0) */         \
    else          { U1(P0.x, v0_.x) }                                   \
    U1(P0.y, v0_.y) U1(P0.z, v0_.z) U1(P0.w, v0_.w)                     \
    U1(P1.x, v1_.x) U1(P1.y, v1_.y) U1(P1.z, v1_.z) U1(P1.w, v1_.w)     \
    U1(P2.x, v2_.x) U1(P2.y, v2_.y) U1(P2.z, v2_.z) U1(P2.w, v2_.w)     \
    U1(P3.x, v3_.x) U1(P3.y, v3_.y) U1(P3.z, v3_.z) U1(P3.w, v3_.w)     \
    float* lp_ = &vbuf[lrow][((cc) & 7) * 16];                          \
    *(float4*)(lp_)     = v0_;  *(float4*)(lp_ + 4)  = v1_;             \
    *(float4*)(lp_ + 8) = v2_;  *(float4*)(lp_ + 12) = v3_; }

// dump chunks [cs, ce) from LDS to global, coalesced: one store instr
// covers 2 rows x 32 lanes x 16B of contiguous full 64B lines.
#define DUMP(cs, ce) {                                                  \
    const int nf4_ = ((ce) - (cs)) * 4;                                 \
    const int l5_ = lane & 31, sub_ = lane >> 5;                        \
    if (l5_ < nf4_) {                                                   \
        for (int r_ = 0; r_ + sub_ < nrow; r_ += 2) {                   \
            int rr_ = r_ + sub_;                                        \
            float4 val_ = *(const float4*)&vbuf[rr_][l5_ * 4];          \
            *(float4*)(out + T + (long)(base + rr_) * T                 \
                       + (cs) * 16 + l5_ * 4) = val_;                   \
        }                                                               \
    }                                                                   \
}

// guarded pipeline step for the epilogue
#define GSTEP(k, PP0, PP1, PP2, PP3, LL0, LL1, LL2, LL3)                \
  if (c + (k) < nch) {                                                  \
    if (c + (k) + 5 < nch) LDm(LL0, LL1, LL2, LL3, c + (k) + 5)         \
    PROCm(PP0, PP1, PP2, PP3, c + (k))                                  \
    if (((c + (k) + 1) & 7) == 0) DUMP(c + (k) + 1 - 8, c + (k) + 1)    \
  }

__global__ __launch_bounds__(64) void sim_nospike(
    const float* __restrict__ Input, const float* __restrict__ dtp,
    float* __restrict__ out, int T, int* __restrict__ flags)
{
    const int lane = threadIdx.x;
    const int b = blockIdx.x;
    __shared__ float vbuf[NPB][LROW];      // 16.9 KB; unused by zero path

    if (b >= NB_SIM) {                       // ---- zeroing path (full-chip BW) ----
        // NT stores: consecutive lanes write consecutive float4s -> 1024B
        // contiguous per wave instr = 16 full 64B lines; also avoids
        // polluting L2 with 60MB of zeros.
        const nf4 z4 = {0.f, 0.f, 0.f, 0.f};
        long zidx = (long)(b - NB_SIM) * 64 + lane;
        long zstr = (long)(NB_TOT - NB_SIM) * 64;
        nf4* gz = (nf4*)(out + T + (long)NT * T);   // g+spk contiguous
        const long n4 = (long)NT * T / 2;
        for (long k = zidx; k < n4; k += zstr) __builtin_nontemporal_store(z4, gz + k);
        if (b == NB_SIM) {
            nf4* oz = (nf4*)out;
            for (int x = lane; x < T / 4; x += 64) __builtin_nontemporal_store(z4, oz + x);
        }
        return;
    }

    const int base = b * NPB;
    const int nrow = (NT - base < NPB) ? (NT - base) : NPB;
    const int lrow = lane & 31;              // both half-waves -> same row
    int i = base + lrow; if (i >= NT) i = NT - 1;   // clamp: dup work, benign
    const float dt = dtp[0];
    const float gl = (i < NE) ? 0.08f : 0.1f;
    const float kk = (2.0f / 7.0f) * dt;     // C0*dt
    const float hh = 0.5f * gl * dt;
    const float mh = -hh;
    const float* ip = Input + (long)i * T;
    float* vrow = out + T + (long)i * T;     // scalar-tail path only
    float u = 0.f, umax = -1e30f;

    const int nch = ((T & 3) == 0) ? (T >> 4) : 0;    // 16-step chunks (62 @ T=1000)

    // 8 buffer slots, 5 chunks in flight ahead of use.
    float4 s00,s01,s02,s03, s10,s11,s12,s13, s20,s21,s22,s23, s30,s31,s32,s33,
           s40,s41,s42,s43, s50,s51,s52,s53, s60,s61,s62,s63, s70,s71,s72,s73;

    if (nch > 0) LDm(s00,s01,s02,s03, 0)
    if (nch > 1) LDm(s10,s11,s12,s13, 1)
    if (nch > 2) LDm(s20,s21,s22,s23, 2)
    if (nch > 3) LDm(s30,s31,s32,s33, 3)
    if (nch > 4) LDm(s40,s41,s42,s43, 4)

    int c = 0;
    // stationary period-8 rotation: PROC slot k eats chunk c+k, LD slot
    // (k+5)%8 fetches chunk c+k+5. Dump the finished 8-chunk segment at
    // the end of each iteration.
    for (; c + 13 <= nch; c += 8) {
        LDm(s50,s51,s52,s53, c+5)   PROCm(s00,s01,s02,s03, c)
        LDm(s60,s61,s62,s63, c+6)   PROCm(s10,s11,s12,s13, c+1)
        LDm(s70,s71,s72,s73, c+7)   PROCm(s20,s21,s22,s23, c+2)
        LDm(s00,s01,s02,s03, c+8)   PROCm(s30,s31,s32,s33, c+3)
        LDm(s10,s11,s12,s13, c+9)   PROCm(s40,s41,s42,s43, c+4)
        LDm(s20,s21,s22,s23, c+10)  PROCm(s50,s51,s52,s53, c+5)
        LDm(s30,s31,s32,s33, c+11)  PROCm(s60,s61,s62,s63, c+6)
        LDm(s40,s41,s42,s43, c+12)  PROCm(s70,s71,s72,s73, c+7)
        DUMP(c, c + 8)
    }
    // guarded epilogue: up to 12 remaining chunks
    GSTEP(0,  s00,s01,s02,s03, s50,s51,s52,s53)
    GSTEP(1,  s10,s11,s12,s13, s60,s61,s62,s63)
    GSTEP(2,  s20,s21,s22,s23, s70,s71,s72,s73)
    GSTEP(3,  s30,s31,s32,s33, s00,s01,s02,s03)
    GSTEP(4,  s40,s41,s42,s43, s10,s11,s12,s13)
    GSTEP(5,  s50,s51,s52,s53, s20,s21,s22,s23)
    GSTEP(6,  s60,s61,s62,s63, s30,s31,s32,s33)
    GSTEP(7,  s70,s71,s72,s73, s40,s41,s42,s43)
    GSTEP(8,  s00,s01,s02,s03, s50,s51,s52,s53)
    GSTEP(9,  s10,s11,s12,s13, s60,s61,s62,s63)
    GSTEP(10, s20,s21,s22,s23, s70,s71,s72,s73)
    GSTEP(11, s30,s31,s32,s33, s00,s01,s02,s03)

    { const int cd = nch & ~7; if (nch > cd) DUMP(cd, nch) }

    // scalar tail (T=1000 -> 8 steps; also the generic path when T%4 != 0)
    for (int t = nch * 16; t < T; ++t) {
        float w = ip[t], v;
        if (t == 0) { v = -58.5f; }
        else        { U1(w, v) }
        vrow[t] = v;                    // dup lanes write same addr/data: benign
    }

    // conservative spike flag: theta >= pi requires crossing u = tan(theta/2) >= 1
    unsigned long long ball = __ballot(umax >= 1.0f);
    if (lane == 0) flags[b] = (ball != 0ULL) ? 1 : 0;
}

// Exact sequential fallback (only executes if a spike was flagged).
__global__ __launch_bounds__(1024) void fallback(
    const float* __restrict__ Input, const float* __restrict__ conn,
    const float* __restrict__ Wout, const float* __restrict__ dtp,
    const int* __restrict__ tauEp, const int* __restrict__ tauIp,
    float* __restrict__ out, int T, const int* __restrict__ flags, int nb)
{
    __shared__ int any;
    const int tid = threadIdx.x;
    if (tid == 0) any = 0;
    __syncthreads();
    if (tid < nb && flags[tid] != 0) any = 1;
    __syncthreads();
    if (any == 0) return;                   // uniform: optimistic path valid

    const float dt = *dtp;
    const float tauE = (float)(*tauEp), tauI = (float)(*tauIp);
    const float C0 = (float)(2.0 / 7.0);
    const float C1 = (float)(117.0 / 7.0);
    const float C2 = (float)(-23.0 / 7.0);
    const int BLK = 1024;
    const int K = 5;                        // 5*1024 >= 5000

    __shared__ int cntE, cntI;
    __shared__ int listE[NE];
    __shared__ int listI[NI];
    __shared__ float red[1024];

    float gA[K], gB[K], gC[K], ph[K];
    for (int k = 0; k < K; ++k) { gA[k] = gB[k] = gC[k] = 0.f; ph[k] = 0.f; }
    if (tid == 0) { cntE = 0; cntI = 0; }

    float* Vout = out + T;
    float* Gout = out + T + (long)NT * T;
    float* Sout = out + T + 2L * (long)NT * T;
    for (int k = 0; k < K; ++k) {
        int i = tid + k * BLK;
        if (i < NT) Vout[(long)i * T] = -58.5f;
    }
    __syncthreads();

    for (int t = 1; t < T; ++t) {
        int nEs = cntE, nIs = cntI;         // spikes from step t-1
        float outpart = 0.f;
        for (int k = 0; k < K; ++k) {
            int i = tid + k * BLK;
            if (i >= NT) break;
            const float* crow = conn + (long)i * NT;
            float mA = 0.f, mB = 0.f;
            for (int j = 0; j < nEs; ++j) mA += crow[listE[j]];
            for (int j = 0; j < nIs; ++j) mB += crow[listI[j]];
            bool isE = i < NE;
            float tau = isE ? tauE : tauI;
            float gpA = isE ? 0.004069f : 0.003276f;
            float gpB = isE ? 0.02672f  : 0.02138f;
            gA[k] = gA[k] + (-gA[k] / tau + gpA * mA) * dt;
            gB[k] = gB[k] + (-gB[k] / tau + gpB * mB) * dt;
            gC[k] = gC[k] + (-gC[k] / tau + gpA * mA + gpB * mB) * dt;
            Gout[(long)i * T + t] = gC[k];
            outpart += gC[k] * Wout[i];
        }
        __syncthreads();                    // all done reading lists
        if (tid == 0) { cntE = 0; cntI = 0; }
        red[tid] = outpart;
        __syncthreads();
        for (int sd = BLK / 2; sd > 0; sd >>= 1) {
            if (tid < sd) red[tid] += red[tid + sd];
            __syncthreads();
        }
        if (tid == 0) out[t] = red[0] / (float)NT;

        for (int k = 0; k < K; ++k) {
            int i = tid + k * BLK;
            if (i >= NT) break;
            bool isE = i < NE;
            float gl = isE ? 0.08f : 0.1f;
            float inp = Input[(long)i * T + t];
            float s, c;
            sincosf(ph[k], &s, &c);
            float ph2 = ph[k] + (-gl * c + C0 * (1.f + c) * inp
                                 + gA[k] * (C1 * (1.f + c) - s)
                                 + gB[k] * (C2 * (1.f + c) - s)) * dt;
            float spkv = 0.f;
            if (ph2 >= PI_F) {
                spkv = 1.f;
                ph2 -= 2.f * PI_F;
                int pos = isE ? atomicAdd(&cntE, 1) : atomicAdd(&cntI, 1);
                if (isE) listE[pos] = i; else listI[pos] = i;
            }
            ph[k] = ph2;
            Sout[(long)i * T + t] = spkv;
            Vout[(long)i * T + t] = fmaf(3.5f, tanf(ph2 * 0.5f), -58.5f);
        }
        __syncthreads();                    // lists complete for next step
    }
}

extern "C" void kernel_launch(void* const* d_in, const int* in_sizes, int n_in,
                              void* d_out, int out_size, void* d_ws, size_t ws_size,
                              hipStream_t stream)
{
    const float* dt    = (const float*)d_in[0];
    const float* Input = (const float*)d_in[1];
    const float* conn  = (const float*)d_in[2];
    const float* Wout  = (const float*)d_in[3];
    const int*   tauE  = (const int*)d_in[6];
    const int*   tauI  = (const int*)d_in[7];
    int T = in_sizes[1] / NT;
    float* out = (float*)d_out;
    int* flags = (int*)d_ws;

    sim_nospike<<<NB_TOT, 64, 0, stream>>>(Input, dt, out, T, flags);
    fallback<<<1, 1024, 0, stream>>>(Input, conn, Wout, dt, tauE, tauI, out, T, flags, NB_SIM);
}

// Round 6
// 184.148 us; speedup vs baseline: 1.1993x; 1.0555x over previous
//
#include <hip/hip_runtime.h>

#define NE 4000
#define NI 1000
#define NT 5000            // total neurons
#define PI_F 3.14159265358979323846f

// 16 neurons per sim block: 313 sim blocks -> every CU carries a sim wave
// (some carry 2: free TLP). Wave64 issue cost is independent of active
// lanes, so per-wave compute is unchanged (~4us dep-chain floor); per-CU
// memory demand halves vs NPB=32 (~5us), balancing the two pipes.
// Lanes 16-63 duplicate lanes 0-15 (dup loads coalesce to the same lines;
// LDS writes predicated to lane<NPB -> no same-address write hazard).
#define NPB 16
#define NB_SIM ((NT + NPB - 1) / NPB)   // 313 sim blocks
#define NB_TOT 1024                     // rest are zero-filler blocks

// native vector type for __builtin_nontemporal_store (HIP float4 is rejected)
typedef float nf4 __attribute__((ext_vector_type(4)));

#define LROW 132   // LDS row: 128 floats (8 chunks of V) + 4 pad (bank spread)

// d_out layout (floats): [0,T) Out | [T, T+NT*T) V | next NT*T g | next NT*T spk

// One Euler step in u = tan(theta/2):  u += kk*I - hh + hh*u^2 ;  V = 3.5u - 58.5
#define U1(W, VV) { float a_ = fmaf(kk, (W), mh); float s_ = u + a_;    \
                    u = fmaf(hh * u, u, s_); umax = fmaxf(umax, u);     \
                    VV = fmaf(3.5f, u, -58.5f); }

// load one 16-step chunk (4 x dwordx4 = exactly one 64B line per lane;
// quarter-waves duplicate rows -> still 16 unique lines per instr)
#define LDm(P0, P1, P2, P3, cc) { const float* sp_ = ip + (cc) * 16;    \
    P0 = *(const float4*)(sp_);      P1 = *(const float4*)(sp_ + 4);    \
    P2 = *(const float4*)(sp_ + 8);  P3 = *(const float4*)(sp_ + 12); }

// compute 16 steps; write V into LDS (row = lane&15, slot = chunk & 7).
// ds_write lives on lgkmcnt -> store traffic doesn't clog the vmcnt
// queue the prefetch loads wait on (R2 evidence: scattered global
// stores -> 1.56 TB/s, VALUBusy 1.4%, ~95% stall). Writes predicated to
// lane<NPB: 4-way same-address LDS write behavior is unmeasured, exec
// masking is free and provably conflict-free.
#define PROCm(P0, P1, P2, P3, cc) {                                     \
    float4 v0_, v1_, v2_, v3_; int t0_ = (cc) * 16;                     \
    if (t0_ == 0) { v0_.x = -58.5f; }   /* t=0: V=theta2V(0) */         \
    else          { U1(P0.x, v0_.x) }                                   \
    U1(P0.y, v0_.y) U1(P0.z, v0_.z) U1(P0.w, v0_.w)                     \
    U1(P1.x, v1_.x) U1(P1.y, v1_.y) U1(P1.z, v1_.z) U1(P1.w, v1_.w)     \
    U1(P2.x, v2_.x) U1(P2.y, v2_.y) U1(P2.z, v2_.z) U1(P2.w, v2_.w)     \
    U1(P3.x, v3_.x) U1(P3.y, v3_.y) U1(P3.z, v3_.z) U1(P3.w, v3_.w)     \
    if (lane < NPB) {                                                   \
        float* lp_ = &vbuf[lrow][((cc) & 7) * 16];                      \
        *(float4*)(lp_)     = v0_;  *(float4*)(lp_ + 4)  = v1_;         \
        *(float4*)(lp_ + 8) = v2_;  *(float4*)(lp_ + 12) = v3_;         \
    } }

// dump chunks [cs, ce) from LDS to global, coalesced: one store instr
// covers 2 rows x 32 lanes x 16B of contiguous full 64B lines.
#define DUMP(cs, ce) {                                                  \
    const int nf4_ = ((ce) - (cs)) * 4;                                 \
    const int l5_ = lane & 31, sub_ = lane >> 5;                        \
    if (l5_ < nf4_) {                                                   \
        for (int r_ = 0; r_ + sub_ < nrow; r_ += 2) {                   \
            int rr_ = r_ + sub_;                                        \
            float4 val_ = *(const float4*)&vbuf[rr_][l5_ * 4];          \
            *(float4*)(out + T + (long)(base + rr_) * T                 \
                       + (cs) * 16 + l5_ * 4) = val_;                   \
        }                                                               \
    }                                                                   \
}

// guarded pipeline step for the epilogue
#define GSTEP(k, PP0, PP1, PP2, PP3, LL0, LL1, LL2, LL3)                \
  if (c + (k) < nch) {                                                  \
    if (c + (k) + 5 < nch) LDm(LL0, LL1, LL2, LL3, c + (k) + 5)         \
    PROCm(PP0, PP1, PP2, PP3, c + (k))                                  \
    if (((c + (k) + 1) & 7) == 0) DUMP(c + (k) + 1 - 8, c + (k) + 1)    \
  }

__global__ __launch_bounds__(64) void sim_nospike(
    const float* __restrict__ Input, const float* __restrict__ dtp,
    float* __restrict__ out, int T, int* __restrict__ flags)
{
    const int lane = threadIdx.x;
    const int b = blockIdx.x;
    __shared__ float vbuf[NPB][LROW];      // 8.25 KB; unused by zero path

    if (b >= NB_SIM) {                       // ---- zeroing path (full-chip BW) ----
        // NT stores: consecutive lanes write consecutive float4s -> 1024B
        // contiguous per wave instr = 16 full 64B lines; also avoids
        // polluting L2 with 60MB of zeros.
        const nf4 z4 = {0.f, 0.f, 0.f, 0.f};
        long zidx = (long)(b - NB_SIM) * 64 + lane;
        long zstr = (long)(NB_TOT - NB_SIM) * 64;
        nf4* gz = (nf4*)(out + T + (long)NT * T);   // g+spk contiguous
        const long n4 = (long)NT * T / 2;
        for (long k = zidx; k < n4; k += zstr) __builtin_nontemporal_store(z4, gz + k);
        if (b == NB_SIM) {
            nf4* oz = (nf4*)out;
            for (int x = lane; x < T / 4; x += 64) __builtin_nontemporal_store(z4, oz + x);
        }
        return;
    }

    const int base = b * NPB;
    const int nrow = (NT - base < NPB) ? (NT - base) : NPB;
    const int lrow = lane & (NPB - 1);       // all quarter-waves -> same row
    int i = base + lrow; if (i >= NT) i = NT - 1;   // clamp: dup work, benign
    const float dt = dtp[0];
    const float gl = (i < NE) ? 0.08f : 0.1f;
    const float kk = (2.0f / 7.0f) * dt;     // C0*dt
    const float hh = 0.5f * gl * dt;
    const float mh = -hh;
    const float* ip = Input + (long)i * T;
    float* vrow = out + T + (long)i * T;     // scalar-tail path only
    float u = 0.f, umax = -1e30f;

    const int nch = ((T & 3) == 0) ? (T >> 4) : 0;    // 16-step chunks (62 @ T=1000)

    // 8 buffer slots, 5 chunks in flight ahead of use.
    float4 s00,s01,s02,s03, s10,s11,s12,s13, s20,s21,s22,s23, s30,s31,s32,s33,
           s40,s41,s42,s43, s50,s51,s52,s53, s60,s61,s62,s63, s70,s71,s72,s73;

    if (nch > 0) LDm(s00,s01,s02,s03, 0)
    if (nch > 1) LDm(s10,s11,s12,s13, 1)
    if (nch > 2) LDm(s20,s21,s22,s23, 2)
    if (nch > 3) LDm(s30,s31,s32,s33, 3)
    if (nch > 4) LDm(s40,s41,s42,s43, 4)

    int c = 0;
    // stationary period-8 rotation: PROC slot k eats chunk c+k, LD slot
    // (k+5)%8 fetches chunk c+k+5. Dump the finished 8-chunk segment at
    // the end of each iteration.
    for (; c + 13 <= nch; c += 8) {
        LDm(s50,s51,s52,s53, c+5)   PROCm(s00,s01,s02,s03, c)
        LDm(s60,s61,s62,s63, c+6)   PROCm(s10,s11,s12,s13, c+1)
        LDm(s70,s71,s72,s73, c+7)   PROCm(s20,s21,s22,s23, c+2)
        LDm(s00,s01,s02,s03, c+8)   PROCm(s30,s31,s32,s33, c+3)
        LDm(s10,s11,s12,s13, c+9)   PROCm(s40,s41,s42,s43, c+4)
        LDm(s20,s21,s22,s23, c+10)  PROCm(s50,s51,s52,s53, c+5)
        LDm(s30,s31,s32,s33, c+11)  PROCm(s60,s61,s62,s63, c+6)
        LDm(s40,s41,s42,s43, c+12)  PROCm(s70,s71,s72,s73, c+7)
        DUMP(c, c + 8)
    }
    // guarded epilogue: up to 12 remaining chunks
    GSTEP(0,  s00,s01,s02,s03, s50,s51,s52,s53)
    GSTEP(1,  s10,s11,s12,s13, s60,s61,s62,s63)
    GSTEP(2,  s20,s21,s22,s23, s70,s71,s72,s73)
    GSTEP(3,  s30,s31,s32,s33, s00,s01,s02,s03)
    GSTEP(4,  s40,s41,s42,s43, s10,s11,s12,s13)
    GSTEP(5,  s50,s51,s52,s53, s20,s21,s22,s23)
    GSTEP(6,  s60,s61,s62,s63, s30,s31,s32,s33)
    GSTEP(7,  s70,s71,s72,s73, s40,s41,s42,s43)
    GSTEP(8,  s00,s01,s02,s03, s50,s51,s52,s53)
    GSTEP(9,  s10,s11,s12,s13, s60,s61,s62,s63)
    GSTEP(10, s20,s21,s22,s23, s70,s71,s72,s73)
    GSTEP(11, s30,s31,s32,s33, s00,s01,s02,s03)

    { const int cd = nch & ~7; if (nch > cd) DUMP(cd, nch) }

    // scalar tail (T=1000 -> 8 steps; also the generic path when T%4 != 0)
    for (int t = nch * 16; t < T; ++t) {
        float w = ip[t], v;
        if (t == 0) { v = -58.5f; }
        else        { U1(w, v) }
        vrow[t] = v;                    // dup lanes write same addr/data: benign
    }

    // conservative spike flag: theta >= pi requires crossing u = tan(theta/2) >= 1
    unsigned long long ball = __ballot(umax >= 1.0f);
    if (lane == 0) flags[b] = (ball != 0ULL) ? 1 : 0;
}

// Exact sequential fallback (only executes if a spike was flagged).
__global__ __launch_bounds__(1024) void fallback(
    const float* __restrict__ Input, const float* __restrict__ conn,
    const float* __restrict__ Wout, const float* __restrict__ dtp,
    const int* __restrict__ tauEp, const int* __restrict__ tauIp,
    float* __restrict__ out, int T, const int* __restrict__ flags, int nb)
{
    __shared__ int any;
    const int tid = threadIdx.x;
    if (tid == 0) any = 0;
    __syncthreads();
    if (tid < nb && flags[tid] != 0) any = 1;
    __syncthreads();
    if (any == 0) return;                   // uniform: optimistic path valid

    const float dt = *dtp;
    const float tauE = (float)(*tauEp), tauI = (float)(*tauIp);
    const float C0 = (float)(2.0 / 7.0);
    const float C1 = (float)(117.0 / 7.0);
    const float C2 = (float)(-23.0 / 7.0);
    const int BLK = 1024;
    const int K = 5;                        // 5*1024 >= 5000

    __shared__ int cntE, cntI;
    __shared__ int listE[NE];
    __shared__ int listI[NI];
    __shared__ float red[1024];

    float gA[K], gB[K], gC[K], ph[K];
    for (int k = 0; k < K; ++k) { gA[k] = gB[k] = gC[k] = 0.f; ph[k] = 0.f; }
    if (tid == 0) { cntE = 0; cntI = 0; }

    float* Vout = out + T;
    float* Gout = out + T + (long)NT * T;
    float* Sout = out + T + 2L * (long)NT * T;
    for (int k = 0; k < K; ++k) {
        int i = tid + k * BLK;
        if (i < NT) Vout[(long)i * T] = -58.5f;
    }
    __syncthreads();

    for (int t = 1; t < T; ++t) {
        int nEs = cntE, nIs = cntI;         // spikes from step t-1
        float outpart = 0.f;
        for (int k = 0; k < K; ++k) {
            int i = tid + k * BLK;
            if (i >= NT) break;
            const float* crow = conn + (long)i * NT;
            float mA = 0.f, mB = 0.f;
            for (int j = 0; j < nEs; ++j) mA += crow[listE[j]];
            for (int j = 0; j < nIs; ++j) mB += crow[listI[j]];
            bool isE = i < NE;
            float tau = isE ? tauE : tauI;
            float gpA = isE ? 0.004069f : 0.003276f;
            float gpB = isE ? 0.02672f  : 0.02138f;
            gA[k] = gA[k] + (-gA[k] / tau + gpA * mA) * dt;
            gB[k] = gB[k] + (-gB[k] / tau + gpB * mB) * dt;
            gC[k] = gC[k] + (-gC[k] / tau + gpA * mA + gpB * mB) * dt;
            Gout[(long)i * T + t] = gC[k];
            outpart += gC[k] * Wout[i];
        }
        __syncthreads();                    // all done reading lists
        if (tid == 0) { cntE = 0; cntI = 0; }
        red[tid] = outpart;
        __syncthreads();
        for (int sd = BLK / 2; sd > 0; sd >>= 1) {
            if (tid < sd) red[tid] += red[tid + sd];
            __syncthreads();
        }
        if (tid == 0) out[t] = red[0] / (float)NT;

        for (int k = 0; k < K; ++k) {
            int i = tid + k * BLK;
            if (i >= NT) break;
            bool isE = i < NE;
            float gl = isE ? 0.08f : 0.1f;
            float inp = Input[(long)i * T + t];
            float s, c;
            sincosf(ph[k], &s, &c);
            float ph2 = ph[k] + (-gl * c + C0 * (1.f + c) * inp
                                 + gA[k] * (C1 * (1.f + c) - s)
                                 + gB[k] * (C2 * (1.f + c) - s)) * dt;
            float spkv = 0.f;
            if (ph2 >= PI_F) {
                spkv = 1.f;
                ph2 -= 2.f * PI_F;
                int pos = isE ? atomicAdd(&cntE, 1) : atomicAdd(&cntI, 1);
                if (isE) listE[pos] = i; else listI[pos] = i;
            }
            ph[k] = ph2;
            Sout[(long)i * T + t] = spkv;
            Vout[(long)i * T + t] = fmaf(3.5f, tanf(ph2 * 0.5f), -58.5f);
        }
        __syncthreads();                    // lists complete for next step
    }
}

extern "C" void kernel_launch(void* const* d_in, const int* in_sizes, int n_in,
                              void* d_out, int out_size, void* d_ws, size_t ws_size,
                              hipStream_t stream)
{
    const float* dt    = (const float*)d_in[0];
    const float* Input = (const float*)d_in[1];
    const float* conn  = (const float*)d_in[2];
    const float* Wout  = (const float*)d_in[3];
    const int*   tauE  = (const int*)d_in[6];
    const int*   tauI  = (const int*)d_in[7];
    int T = in_sizes[1] / NT;
    float* out = (float*)d_out;
    int* flags = (int*)d_ws;

    sim_nospike<<<NB_TOT, 64, 0, stream>>>(Input, dt, out, T, flags);
    fallback<<<1, 1024, 0, stream>>>(Input, conn, Wout, dt, tauE, tauI, out, T, flags, NB_SIM);
}